// Round 5
// baseline (623.413 us; speedup 1.0000x reference)
//
#include <hip/hip_runtime.h>
#include <stdint.h>

// ---------------------------------------------------------------------------
// Fused: (add+RMSNorm+static fp8 quant) -> MX-fp8 GEMM (scale=1.0) -> dequant
// T=8192, H=4096, I=8192 (derived from in_sizes at launch)
// d_out = [ out f32 [T][I] | residual_out f32 [T][H] ]
// d_ws  = [ q' fp8 frag-tiles | wt' fp8 frag-tiles ]
//
// Fragment-tile layout (both operands; tile = 128 rows x 64 k-bytes = 8 KB):
//   tile_idx = (row>>7)*(K/64) + (k>>6)
//   chunk c  = s*4 + kc*2 + p   (s=(row>>5)&3, kc=(k>>5)&1, p=(k>>4)&1)
//   offset   = tile_idx*8192 + c*512 + (row&31)*16 + (k&15)
// Frag reads are lane-linear ds_read_b128 (measured 0 bank conflicts).
//
// GEMM: 256x256 tile, 8 waves (2Mx4N, wave tile 128x64), m201-style 8-phase
// barrier-pair schedule: iteration = 2 tranches (BK=128B); each phase =
// {ds-reads + 1 staging gload -> s_barrier -> lgkmcnt(0) -> setprio(1)
//  2x mfma_scale 32x32x64 -> setprio(0) -> s_barrier}. Counted vmcnt(4) only
// at phases 0 and 4 (never drains to 0). LDS = 2 buf x 2 tranche x 32 KB.
// vmcnt ledger: at each wait, outstanding = 8 (4 for entering tranche issued
// one iter ago + 4 for the following tranche); vmcnt(4) drains exactly the
// entering tranche. Phase-0/4 reads are AFTER the barrier (cross-wave gload
// visibility requires all waves past their vmcnt before any wave reads).
// ---------------------------------------------------------------------------

typedef float float16v __attribute__((ext_vector_type(16)));
typedef int   int8v    __attribute__((ext_vector_type(8)));

#define GLOAD_LDS16(gp, lp)                                                    \
    __builtin_amdgcn_global_load_lds(                                          \
        (const __attribute__((address_space(1))) void*)(gp),                   \
        (__attribute__((address_space(3))) void*)(lp), 16, 0, 0)

#define MFMA_SCALE1(a, b, c)                                                   \
    __builtin_amdgcn_mfma_scale_f32_32x32x64_f8f6f4(                           \
        (a), (b), (c), 0, 0, 0, 0x7f7f7f7f, 0, 0x7f7f7f7f)

// ---------------------------------------------------------------------------
// Kernel 1: w f32 [K][N] -> fp8 fragment-tiles wt' (transpose: rows = n)
// ---------------------------------------------------------------------------
__global__ void __launch_bounds__(256) wconv_kernel(
    const float* __restrict__ w, uint8_t* __restrict__ wt, int K, int N) {
    __shared__ uint8_t tile[64 * 64];  // [n_local][k_local]
    const int k0 = blockIdx.y * 64;
    const int n0 = blockIdx.x * 64;
    const int t = threadIdx.x;
    const int c4 = t & 15;   // n-chunk of 4 floats
    const int r = t >> 4;    // k row base (0..15)

#pragma unroll
    for (int p = 0; p < 4; ++p) {
        const int k = r + p * 16;
        const float4 v = *(const float4*)(w + (size_t)(k0 + k) * N + n0 + c4 * 4);
        const int pk0 = __builtin_amdgcn_cvt_pk_fp8_f32(v.x, v.y, 0, false);
        const int pk1 = __builtin_amdgcn_cvt_pk_fp8_f32(v.z, v.w, 0, false);
        tile[(c4 * 4 + 0) * 64 + k] = (uint8_t)(pk0 & 0xff);
        tile[(c4 * 4 + 1) * 64 + k] = (uint8_t)((pk0 >> 8) & 0xff);
        tile[(c4 * 4 + 2) * 64 + k] = (uint8_t)(pk1 & 0xff);
        tile[(c4 * 4 + 3) * 64 + k] = (uint8_t)((pk1 >> 8) & 0xff);
    }
    __syncthreads();
    const int n_local = t >> 2;
    const int ch = t & 3;   // 16B piece within 64B k-group: c = s*4 + ch
    const uint4 val = *(const uint4*)(&tile[n_local * 64 + ch * 16]);
    const int n = n0 + n_local;
    const size_t tile_idx = (size_t)(n >> 7) * (K >> 6) + (k0 >> 6);
    const int c = ((n >> 5) & 3) * 4 + ch;
    *(uint4*)(wt + tile_idx * 8192 + c * 512 + (n & 31) * 16) = val;
}

// ---------------------------------------------------------------------------
// Kernel 2: residual_out = hs + res; RMSNorm; q' = fp8(norm/scale) frag-tiles
// ---------------------------------------------------------------------------
__global__ void __launch_bounds__(256) norm_quant_kernel(
    const float* __restrict__ hs, const float* __restrict__ res,
    const float* __restrict__ nw, const float* __restrict__ scale,
    float* __restrict__ resid_out, uint8_t* __restrict__ q, int H) {
    __shared__ float sm[4096];
    __shared__ float wsum[4];
    __shared__ float s_inv;
    const int row = blockIdx.x;
    const int t = threadIdx.x;
    const float* hrow = hs + (size_t)row * H;
    const float* rrow = res + (size_t)row * H;
    float* orow = resid_out + (size_t)row * H;

    float acc = 0.f;
#pragma unroll
    for (int p = 0; p < 4; ++p) {
        const int c = p * 1024 + t * 4;
        const float4 h = *(const float4*)(hrow + c);
        const float4 r = *(const float4*)(rrow + c);
        float4 s;
        s.x = h.x + r.x; s.y = h.y + r.y; s.z = h.z + r.z; s.w = h.w + r.w;
        *(float4*)(orow + c) = s;
        *(float4*)(&sm[c]) = s;
        acc += s.x * s.x + s.y * s.y + s.z * s.z + s.w * s.w;
    }
#pragma unroll
    for (int off = 32; off; off >>= 1) acc += __shfl_down(acc, off);
    if ((t & 63) == 0) wsum[t >> 6] = acc;
    __syncthreads();
    if (t == 0) {
        const float tot = wsum[0] + wsum[1] + wsum[2] + wsum[3];
        s_inv = 1.0f / sqrtf(tot / (float)H + 1e-6f);
    }
    __syncthreads();
    const float inv = s_inv;
    const float sval = scale[0];

    // pass 2: thread t quantizes elements [t*16, t*16+16)
    const int k0 = t * 16;
    uint32_t words[4];
#pragma unroll
    for (int i = 0; i < 4; ++i) {
        const float4 s = *(const float4*)(&sm[k0 + i * 4]);
        const float4 wv = *(const float4*)(nw + k0 + i * 4);
        float q0 = (s.x * inv * wv.x) / sval;
        float q1 = (s.y * inv * wv.y) / sval;
        float q2 = (s.z * inv * wv.z) / sval;
        float q3 = (s.w * inv * wv.w) / sval;
        q0 = fminf(fmaxf(q0, -448.f), 448.f);
        q1 = fminf(fmaxf(q1, -448.f), 448.f);
        q2 = fminf(fmaxf(q2, -448.f), 448.f);
        q3 = fminf(fmaxf(q3, -448.f), 448.f);
        int pk = __builtin_amdgcn_cvt_pk_fp8_f32(q0, q1, 0, false);
        pk = __builtin_amdgcn_cvt_pk_fp8_f32(q2, q3, pk, true);
        words[i] = (uint32_t)pk;
    }
    const int kt = t >> 2;           // k-tile (64B groups)
    const int ch = t & 3;            // 16B piece
    const size_t tile_idx = (size_t)(row >> 7) * (H >> 6) + kt;
    const int c = ((row >> 5) & 3) * 4 + ch;
    uint4 val;
    val.x = words[0]; val.y = words[1]; val.z = words[2]; val.w = words[3];
    *(uint4*)(q + tile_idx * 8192 + c * 512 + (row & 31) * 16) = val;
}

// ---------------------------------------------------------------------------
// helper: load one 32-byte MFMA operand frag from a 2KB frag sub-block
// ---------------------------------------------------------------------------
static __device__ __forceinline__ int8v ldfrag(const uint8_t* p) {
    const uint4 lo = *(const uint4*)p;
    const uint4 hi = *(const uint4*)(p + 512);
    int8v r = {(int)lo.x, (int)lo.y, (int)lo.z, (int)lo.w,
               (int)hi.x, (int)hi.y, (int)hi.z, (int)hi.w};
    return r;
}

// ---------------------------------------------------------------------------
// Kernel 3: MX-fp8 GEMM  C[M][N] = (A[M][K] @ B[N][K]^T) * (scale*wscale)
// 256x256 tile, 8 waves (2Mx4N, 128x64 each), m201 8-phase schedule.
// ---------------------------------------------------------------------------
__global__ void __launch_bounds__(512, 2) gemm_fp8_kernel(
    const uint8_t* __restrict__ A,   // q'  frag-tiles
    const uint8_t* __restrict__ B,   // wt' frag-tiles
    float* __restrict__ C,           // out [M][N]
    const float* __restrict__ scale, const float* __restrict__ wscale,
    int M, int N, int K) {
    // 2 buffers x 2 tranches x 32 KB (tranche = A0|A1|B0|B1, 8 KB each)
    __shared__ uint8_t lds[2 * 65536];

    const int t = threadIdx.x;       // 0..511
    const int wid = t >> 6;          // 0..7
    const int lane = t & 63;
    const int wr = wid >> 2;         // 0..1  (M)
    const int wc = wid & 3;          // 0..3  (N)

    // XCD-bijective swizzle (gridDim.x == 1024, %8 == 0)
    const int id = blockIdx.x;
    const int wg = (id & 7) * ((int)gridDim.x >> 3) + (id >> 3);
    const int nbn = N >> 8;
    const int bm = wg / nbn;
    const int bn = wg % nbn;

    const int nkt = K >> 6;          // 64 tranches of 64 fp8 elements
    const int niter = nkt >> 1;      // 32 iterations (2 tranches each)
    const uint8_t* a0s = A + (size_t)(2 * bm) * nkt * 8192;
    const uint8_t* a1s = a0s + (size_t)nkt * 8192;
    const uint8_t* b0s = B + (size_t)(2 * bn) * nkt * 8192;
    const uint8_t* b1s = b0s + (size_t)nkt * 8192;
    const int o16 = t * 16;          // 512 threads x 16B = one 8KB piece

    // per-wave frag offsets within a 32 KB tranche image
    const int lgrp = (lane >> 5) * 1024;
    const int lrow = (lane & 31) * 16;
    const int r32b = wr * 4;
    const int aoff0 = ((r32b + 0) >> 2) * 8192 + ((r32b + 0) & 3) * 2048 + lgrp + lrow;
    const int aoff1 = ((r32b + 1) >> 2) * 8192 + ((r32b + 1) & 3) * 2048 + lgrp + lrow;
    const int aoff2 = ((r32b + 2) >> 2) * 8192 + ((r32b + 2) & 3) * 2048 + lgrp + lrow;
    const int aoff3 = ((r32b + 3) >> 2) * 8192 + ((r32b + 3) & 3) * 2048 + lgrp + lrow;
    const int c32b = wc * 2;
    const int boff0 = 16384 + ((c32b + 0) >> 2) * 8192 + ((c32b + 0) & 3) * 2048 + lgrp + lrow;
    const int boff1 = 16384 + ((c32b + 1) >> 2) * 8192 + ((c32b + 1) & 3) * 2048 + lgrp + lrow;

    float16v acc[4][2] = {};

    // prologue: stage tranches 0,1 into buffer 0 (8 gloads outstanding)
    GLOAD_LDS16(a0s + o16, lds + o16);
    GLOAD_LDS16(a1s + o16, lds + 8192 + o16);
    GLOAD_LDS16(b0s + o16, lds + 16384 + o16);
    GLOAD_LDS16(b1s + o16, lds + 24576 + o16);
    GLOAD_LDS16(a0s + 8192 + o16, lds + 32768 + o16);
    GLOAD_LDS16(a1s + 8192 + o16, lds + 40960 + o16);
    GLOAD_LDS16(b0s + 8192 + o16, lds + 49152 + o16);
    GLOAD_LDS16(b1s + 8192 + o16, lds + 57344 + o16);

    int8v bfr0, bfr1;

// phase tail: drain LDS reads, cluster 2 MFMAs under setprio, close barrier
#define PH_MFMA(AFR, MB)                                                       \
    asm volatile("s_waitcnt lgkmcnt(0)" ::: "memory");                         \
    __builtin_amdgcn_sched_barrier(0);                                         \
    __builtin_amdgcn_s_setprio(1);                                             \
    acc[MB][0] = MFMA_SCALE1(AFR, bfr0, acc[MB][0]);                           \
    acc[MB][1] = MFMA_SCALE1(AFR, bfr1, acc[MB][1]);                           \
    __builtin_amdgcn_s_setprio(0);                                             \
    __builtin_amdgcn_s_barrier();

    int buf = 0;
    for (int i = 0; i < niter; ++i) {
        const uint8_t* sl0 = lds + buf * 65536;          // tranche 2i image
        const uint8_t* sl1 = sl0 + 32768;                // tranche 2i+1 image
        uint8_t* ob = lds + (buf ^ 1) * 65536;
        // next-iter tranche indices (clamped at tail; junk lands in the
        // buffer that is never read again; vmcnt ledger stays uniform)
        const int nt0 = (2 * i + 2 < nkt) ? (2 * i + 2) : (nkt - 1);
        const int nt1 = (2 * i + 3 < nkt) ? (2 * i + 3) : (nkt - 1);
        const size_t s0 = (size_t)nt0 * 8192 + o16;
        const size_t s1 = (size_t)nt1 * 8192 + o16;

        // ---- phase 0 (tranche 0, mb 0) : counted vmcnt, reads after barrier
        asm volatile("s_waitcnt vmcnt(4)" ::: "memory");
        GLOAD_LDS16(a0s + s0, ob + o16);
        __builtin_amdgcn_s_barrier();
        __builtin_amdgcn_sched_barrier(0);
        bfr0 = ldfrag(sl0 + boff0);
        bfr1 = ldfrag(sl0 + boff1);
        {
            const int8v af = ldfrag(sl0 + aoff0);
            PH_MFMA(af, 0)
        }
        // ---- phase 1 (tranche 0, mb 1)
        {
            const int8v af = ldfrag(sl0 + aoff1);
            GLOAD_LDS16(a1s + s0, ob + 8192 + o16);
            __builtin_amdgcn_s_barrier();
            PH_MFMA(af, 1)
        }
        // ---- phase 2 (tranche 0, mb 2)
        {
            const int8v af = ldfrag(sl0 + aoff2);
            GLOAD_LDS16(b0s + s0, ob + 16384 + o16);
            __builtin_amdgcn_s_barrier();
            PH_MFMA(af, 2)
        }
        // ---- phase 3 (tranche 0, mb 3)
        {
            const int8v af = ldfrag(sl0 + aoff3);
            GLOAD_LDS16(b1s + s0, ob + 24576 + o16);
            __builtin_amdgcn_s_barrier();
            PH_MFMA(af, 3)
        }
        // ---- phase 4 (tranche 1, mb 0) : counted vmcnt, reads after barrier
        asm volatile("s_waitcnt vmcnt(4)" ::: "memory");
        GLOAD_LDS16(a0s + s1, ob + 32768 + o16);
        __builtin_amdgcn_s_barrier();
        __builtin_amdgcn_sched_barrier(0);
        bfr0 = ldfrag(sl1 + boff0);
        bfr1 = ldfrag(sl1 + boff1);
        {
            const int8v af = ldfrag(sl1 + aoff0);
            PH_MFMA(af, 0)
        }
        // ---- phase 5 (tranche 1, mb 1)
        {
            const int8v af = ldfrag(sl1 + aoff1);
            GLOAD_LDS16(a1s + s1, ob + 40960 + o16);
            __builtin_amdgcn_s_barrier();
            PH_MFMA(af, 1)
        }
        // ---- phase 6 (tranche 1, mb 2)
        {
            const int8v af = ldfrag(sl1 + aoff2);
            GLOAD_LDS16(b0s + s1, ob + 49152 + o16);
            __builtin_amdgcn_s_barrier();
            PH_MFMA(af, 2)
        }
        // ---- phase 7 (tranche 1, mb 3)
        {
            const int8v af = ldfrag(sl1 + aoff3);
            GLOAD_LDS16(b1s + s1, ob + 57344 + o16);
            __builtin_amdgcn_s_barrier();
            PH_MFMA(af, 3)
        }
        buf ^= 1;
    }
#undef PH_MFMA

    // epilogue: C/D 32x32 layout col=lane&31, row=(reg&3)+8*(reg>>2)+4*(lane>>5)
    const float f = scale[0] * wscale[0];
    const int col = lane & 31;
    const int rb4 = (lane >> 5) * 4;
#pragma unroll
    for (int mb = 0; mb < 4; ++mb) {
#pragma unroll
        for (int nb = 0; nb < 2; ++nb) {
#pragma unroll
            for (int reg = 0; reg < 16; ++reg) {
                const int r = (reg & 3) + 8 * (reg >> 2) + rb4;
                const size_t gr = (size_t)(bm * 256 + wr * 128 + mb * 32 + r);
                const size_t gc = (size_t)(bn * 256 + wc * 64 + nb * 32 + col);
                C[gr * N + gc] = acc[mb][nb][reg] * f;
            }
        }
    }
}

// ---------------------------------------------------------------------------
extern "C" void kernel_launch(void* const* d_in, const int* in_sizes, int n_in,
                              void* d_out, int out_size, void* d_ws, size_t ws_size,
                              hipStream_t stream) {
    const float* hs     = (const float*)d_in[0];
    const float* res    = (const float*)d_in[1];
    const float* nw     = (const float*)d_in[2];
    const float* w      = (const float*)d_in[3];
    const float* scale  = (const float*)d_in[4];
    const float* wscale = (const float*)d_in[5];

    const int H = in_sizes[2];
    const int T = in_sizes[0] / H;
    const int I = in_sizes[3] / H;

    float* out       = (float*)d_out;            // [T][I]
    float* resid_out = out + (size_t)T * I;      // [T][H]
    uint8_t* q  = (uint8_t*)d_ws;                // q'  frag-tiles (T*H bytes)
    uint8_t* wt = q + (size_t)T * H;             // wt' frag-tiles (I*H bytes)

    // 1. weight convert + transpose -> fragment tiles
    wconv_kernel<<<dim3(I / 64, H / 64), 256, 0, stream>>>(w, wt, H, I);
    // 2. fused add + RMSNorm + static fp8 quant -> fragment tiles
    norm_quant_kernel<<<T, 256, 0, stream>>>(hs, res, nw, scale, resid_out, q, H);
    // 3. MX-fp8 GEMM + dequant (256x256 tiles, 8-phase schedule)
    gemm_fp8_kernel<<<(T / 256) * (I / 256), 512, 0, stream>>>(
        q, wt, out, scale, wscale, T, I, H);
}

// Round 6
// 559.336 us; speedup vs baseline: 1.1146x; 1.1146x over previous
//
#include <hip/hip_runtime.h>
#include <stdint.h>

// ---------------------------------------------------------------------------
// Fused: (add+RMSNorm+static fp8 quant) -> MX-fp8 GEMM (scale=1.0) -> dequant
// T=8192, H=4096, I=8192 (derived from in_sizes at launch)
// d_out = [ out f32 [T][I] | residual_out f32 [T][H] ]
// d_ws  = [ q' fp8 frag-tiles | wt' fp8 frag-tiles ]
//
// Fragment-tile layout (both operands; tile = 128 rows x 64 k-bytes = 8 KB):
//   tile_idx = (row>>7)*(K/64) + (k>>6)
//   chunk c  = s*4 + kc*2 + p   (s=(row>>5)&3, kc=(k>>5)&1, p=(k>>4)&1)
//   offset   = tile_idx*8192 + c*512 + (row&31)*16 + (k&15)
// Frag reads are lane-linear ds_read_b128 (measured 0 bank conflicts).
//
// GEMM (R6): 256x256 block tile, 4 waves (2x2), wave tile 128x128.
// Per tranche (64 k-bytes) each wave: 8 frag loads (4 A + 4 B, 16 ds_read_b128)
// feeding 16 INDEPENDENT mfma_scale 32x32x64 -> 1100-cyc matrix-pipe run,
// compiler-scheduled (counted lgkmcnt interleave). One counted vmcnt(8) +
// one s_barrier per tranche; 3-slot LDS rotation (96 KB), prefetch depth 2.
// 1 wave/SIMD by design (ILP hides latency, not TLP): __launch_bounds__(256,1),
// ~360 VGPRs used of the 512 single-wave budget.
// vmcnt ledger: steady state 16 outstanding (8 per prefetched tranche);
// vmcnt(8) at iter kt drains exactly tranche kt. Never drains to 0.
// Slot hazard: writes at iter kt go to slot (kt+2)%3 = (kt-1)%3, whose
// readers (iter kt-1) completed all ds_reads before their barrier arrival
// (every read feeds an MFMA issued pre-barrier); gloads issue post-barrier.
// ---------------------------------------------------------------------------

typedef float float16v __attribute__((ext_vector_type(16)));
typedef int   int8v    __attribute__((ext_vector_type(8)));

#define GLOAD_LDS16(gp, lp)                                                    \
    __builtin_amdgcn_global_load_lds(                                          \
        (const __attribute__((address_space(1))) void*)(gp),                   \
        (__attribute__((address_space(3))) void*)(lp), 16, 0, 0)

#define MFMA_SCALE1(a, b, c)                                                   \
    __builtin_amdgcn_mfma_scale_f32_32x32x64_f8f6f4(                           \
        (a), (b), (c), 0, 0, 0, 0x7f7f7f7f, 0, 0x7f7f7f7f)

// ---------------------------------------------------------------------------
// Kernel 1: w f32 [K][N] -> fp8 fragment-tiles wt' (transpose: rows = n)
// ---------------------------------------------------------------------------
__global__ void __launch_bounds__(256) wconv_kernel(
    const float* __restrict__ w, uint8_t* __restrict__ wt, int K, int N) {
    __shared__ uint8_t tile[64 * 64];  // [n_local][k_local]
    const int k0 = blockIdx.y * 64;
    const int n0 = blockIdx.x * 64;
    const int t = threadIdx.x;
    const int c4 = t & 15;   // n-chunk of 4 floats
    const int r = t >> 4;    // k row base (0..15)

#pragma unroll
    for (int p = 0; p < 4; ++p) {
        const int k = r + p * 16;
        const float4 v = *(const float4*)(w + (size_t)(k0 + k) * N + n0 + c4 * 4);
        const int pk0 = __builtin_amdgcn_cvt_pk_fp8_f32(v.x, v.y, 0, false);
        const int pk1 = __builtin_amdgcn_cvt_pk_fp8_f32(v.z, v.w, 0, false);
        tile[(c4 * 4 + 0) * 64 + k] = (uint8_t)(pk0 & 0xff);
        tile[(c4 * 4 + 1) * 64 + k] = (uint8_t)((pk0 >> 8) & 0xff);
        tile[(c4 * 4 + 2) * 64 + k] = (uint8_t)(pk1 & 0xff);
        tile[(c4 * 4 + 3) * 64 + k] = (uint8_t)((pk1 >> 8) & 0xff);
    }
    __syncthreads();
    const int n_local = t >> 2;
    const int ch = t & 3;   // 16B piece within 64B k-group: c = s*4 + ch
    const uint4 val = *(const uint4*)(&tile[n_local * 64 + ch * 16]);
    const int n = n0 + n_local;
    const size_t tile_idx = (size_t)(n >> 7) * (K >> 6) + (k0 >> 6);
    const int c = ((n >> 5) & 3) * 4 + ch;
    *(uint4*)(wt + tile_idx * 8192 + c * 512 + (n & 31) * 16) = val;
}

// ---------------------------------------------------------------------------
// Kernel 2: residual_out = hs + res; RMSNorm; q' = fp8(norm/scale) frag-tiles
// ---------------------------------------------------------------------------
__global__ void __launch_bounds__(256) norm_quant_kernel(
    const float* __restrict__ hs, const float* __restrict__ res,
    const float* __restrict__ nw, const float* __restrict__ scale,
    float* __restrict__ resid_out, uint8_t* __restrict__ q, int H) {
    __shared__ float sm[4096];
    __shared__ float wsum[4];
    __shared__ float s_inv;
    const int row = blockIdx.x;
    const int t = threadIdx.x;
    const float* hrow = hs + (size_t)row * H;
    const float* rrow = res + (size_t)row * H;
    float* orow = resid_out + (size_t)row * H;

    float acc = 0.f;
#pragma unroll
    for (int p = 0; p < 4; ++p) {
        const int c = p * 1024 + t * 4;
        const float4 h = *(const float4*)(hrow + c);
        const float4 r = *(const float4*)(rrow + c);
        float4 s;
        s.x = h.x + r.x; s.y = h.y + r.y; s.z = h.z + r.z; s.w = h.w + r.w;
        *(float4*)(orow + c) = s;
        *(float4*)(&sm[c]) = s;
        acc += s.x * s.x + s.y * s.y + s.z * s.z + s.w * s.w;
    }
#pragma unroll
    for (int off = 32; off; off >>= 1) acc += __shfl_down(acc, off);
    if ((t & 63) == 0) wsum[t >> 6] = acc;
    __syncthreads();
    if (t == 0) {
        const float tot = wsum[0] + wsum[1] + wsum[2] + wsum[3];
        s_inv = 1.0f / sqrtf(tot / (float)H + 1e-6f);
    }
    __syncthreads();
    const float inv = s_inv;
    const float sval = scale[0];

    // pass 2: thread t quantizes elements [t*16, t*16+16)
    const int k0 = t * 16;
    uint32_t words[4];
#pragma unroll
    for (int i = 0; i < 4; ++i) {
        const float4 s = *(const float4*)(&sm[k0 + i * 4]);
        const float4 wv = *(const float4*)(nw + k0 + i * 4);
        float q0 = (s.x * inv * wv.x) / sval;
        float q1 = (s.y * inv * wv.y) / sval;
        float q2 = (s.z * inv * wv.z) / sval;
        float q3 = (s.w * inv * wv.w) / sval;
        q0 = fminf(fmaxf(q0, -448.f), 448.f);
        q1 = fminf(fmaxf(q1, -448.f), 448.f);
        q2 = fminf(fmaxf(q2, -448.f), 448.f);
        q3 = fminf(fmaxf(q3, -448.f), 448.f);
        int pk = __builtin_amdgcn_cvt_pk_fp8_f32(q0, q1, 0, false);
        pk = __builtin_amdgcn_cvt_pk_fp8_f32(q2, q3, pk, true);
        words[i] = (uint32_t)pk;
    }
    const int kt = t >> 2;           // k-tile (64B groups)
    const int ch = t & 3;            // 16B piece
    const size_t tile_idx = (size_t)(row >> 7) * (H >> 6) + kt;
    const int c = ((row >> 5) & 3) * 4 + ch;
    uint4 val;
    val.x = words[0]; val.y = words[1]; val.z = words[2]; val.w = words[3];
    *(uint4*)(q + tile_idx * 8192 + c * 512 + (row & 31) * 16) = val;
}

// ---------------------------------------------------------------------------
// helper: load one 32-byte MFMA operand frag from a 2KB frag sub-block
// ---------------------------------------------------------------------------
static __device__ __forceinline__ int8v ldfrag(const uint8_t* p) {
    const uint4 lo = *(const uint4*)p;
    const uint4 hi = *(const uint4*)(p + 512);
    int8v r = {(int)lo.x, (int)lo.y, (int)lo.z, (int)lo.w,
               (int)hi.x, (int)hi.y, (int)hi.z, (int)hi.w};
    return r;
}

// ---------------------------------------------------------------------------
// Kernel 3: MX-fp8 GEMM  C[M][N] = (A[M][K] @ B[N][K]^T) * (scale*wscale)
// 256x256 tile, 4 waves (2x2, wave tile 128x128), 16-MFMA ILP per tranche.
// ---------------------------------------------------------------------------
__global__ void __launch_bounds__(256, 1) gemm_fp8_kernel(
    const uint8_t* __restrict__ A,   // q'  frag-tiles
    const uint8_t* __restrict__ B,   // wt' frag-tiles
    float* __restrict__ C,           // out [M][N]
    const float* __restrict__ scale, const float* __restrict__ wscale,
    int M, int N, int K) {
    // 3 slots x 32 KB: slot = Atile0|Atile1|Btile0|Btile1 (8 KB each)
    __shared__ uint8_t lds[3 * 32768];

    const int t = threadIdx.x;       // 0..255
    const int wid = t >> 6;          // 0..3
    const int lane = t & 63;
    const int wr = wid >> 1;         // 0..1  (M)
    const int wc = wid & 1;          // 0..1  (N)

    // XCD-bijective swizzle (gridDim.x == 1024, %8 == 0)
    const int id = blockIdx.x;
    const int wg = (id & 7) * ((int)gridDim.x >> 3) + (id >> 3);
    const int nbn = N >> 8;
    const int bm = wg / nbn;
    const int bn = wg % nbn;

    const int nkt = K >> 6;          // 64 tranches of 64 fp8 k-bytes
    const uint8_t* a0s = A + (size_t)(2 * bm) * nkt * 8192;
    const uint8_t* a1s = a0s + (size_t)nkt * 8192;
    const uint8_t* b0s = B + (size_t)(2 * bn) * nkt * 8192;
    const uint8_t* b1s = b0s + (size_t)nkt * 8192;
    const int o16 = t * 16;          // [0, 4096): 256 threads x 16B per gload

    // per-wave frag offsets within a 32 KB slot
    const int lgrp = (lane >> 5) * 1024;
    const int lrow = (lane & 31) * 16;
    const int abase = wr * 8192 + lgrp + lrow;            // A image at 0
    const int bbase = 16384 + wc * 8192 + lgrp + lrow;    // B image at 16K

    float16v acc[4][4] = {};

    // prologue: stage tranches 0,1 into slots 0,1 (8 gloads each)
#pragma unroll
    for (int u = 0; u < 2; ++u) {
        uint8_t* dst = lds + u * 32768;
        const size_t ofs = (size_t)u * 8192 + o16;
        GLOAD_LDS16(a0s + ofs,        dst + o16);
        GLOAD_LDS16(a0s + ofs + 4096, dst + 4096 + o16);
        GLOAD_LDS16(a1s + ofs,        dst + 8192 + o16);
        GLOAD_LDS16(a1s + ofs + 4096, dst + 12288 + o16);
        GLOAD_LDS16(b0s + ofs,        dst + 16384 + o16);
        GLOAD_LDS16(b0s + ofs + 4096, dst + 20480 + o16);
        GLOAD_LDS16(b1s + ofs,        dst + 24576 + o16);
        GLOAD_LDS16(b1s + ofs + 4096, dst + 28672 + o16);
    }

    int cur = 0, pfs = 2;
    for (int kt = 0; kt < nkt; ++kt) {
        // tranche kt landed iff own outstanding <= 8 (only kt+1 in flight)
        asm volatile("s_waitcnt vmcnt(8)" ::: "memory");
        __builtin_amdgcn_s_barrier();

        const uint8_t* sl = lds + cur * 32768;
        uint8_t* pd = lds + pfs * 32768;
        // tail clamp: junk lands in slot (kt+2)%3, mod-3 distinct from the
        // remaining read slot (kt+1)%3; vmcnt ledger stays uniform.
        const int pf = (kt + 2 < nkt) ? (kt + 2) : (nkt - 1);
        const size_t pofs = (size_t)pf * 8192 + o16;
        GLOAD_LDS16(a0s + pofs,        pd + o16);
        GLOAD_LDS16(a0s + pofs + 4096, pd + 4096 + o16);
        GLOAD_LDS16(a1s + pofs,        pd + 8192 + o16);
        GLOAD_LDS16(a1s + pofs + 4096, pd + 12288 + o16);
        GLOAD_LDS16(b0s + pofs,        pd + 16384 + o16);
        GLOAD_LDS16(b0s + pofs + 4096, pd + 20480 + o16);
        GLOAD_LDS16(b1s + pofs,        pd + 24576 + o16);
        GLOAD_LDS16(b1s + pofs + 4096, pd + 28672 + o16);

        // 8 frag loads (16 ds_read_b128) -> 16 independent MFMAs;
        // compiler interleaves with counted lgkmcnt.
        int8v a[4], b[4];
#pragma unroll
        for (int i = 0; i < 4; ++i) a[i] = ldfrag(sl + abase + i * 2048);
#pragma unroll
        for (int j = 0; j < 4; ++j) b[j] = ldfrag(sl + bbase + j * 2048);
#pragma unroll
        for (int i = 0; i < 4; ++i)
#pragma unroll
            for (int j = 0; j < 4; ++j)
                acc[i][j] = MFMA_SCALE1(a[i], b[j], acc[i][j]);

        cur = (cur == 2) ? 0 : cur + 1;
        pfs = (pfs == 2) ? 0 : pfs + 1;
    }

    // epilogue: C/D 32x32 layout col=lane&31, row=(reg&3)+8*(reg>>2)+4*(lane>>5)
    const float f = scale[0] * wscale[0];
    const int col = lane & 31;
    const int rb4 = (lane >> 5) * 4;
#pragma unroll
    for (int mb = 0; mb < 4; ++mb) {
#pragma unroll
        for (int nb = 0; nb < 4; ++nb) {
#pragma unroll
            for (int reg = 0; reg < 16; ++reg) {
                const int r = (reg & 3) + 8 * (reg >> 2) + rb4;
                const size_t gr = (size_t)(bm * 256 + wr * 128 + mb * 32 + r);
                const size_t gc = (size_t)(bn * 256 + wc * 128 + nb * 32 + col);
                C[gr * N + gc] = acc[mb][nb][reg] * f;
            }
        }
    }
}

// ---------------------------------------------------------------------------
extern "C" void kernel_launch(void* const* d_in, const int* in_sizes, int n_in,
                              void* d_out, int out_size, void* d_ws, size_t ws_size,
                              hipStream_t stream) {
    const float* hs     = (const float*)d_in[0];
    const float* res    = (const float*)d_in[1];
    const float* nw     = (const float*)d_in[2];
    const float* w      = (const float*)d_in[3];
    const float* scale  = (const float*)d_in[4];
    const float* wscale = (const float*)d_in[5];

    const int H = in_sizes[2];
    const int T = in_sizes[0] / H;
    const int I = in_sizes[3] / H;

    float* out       = (float*)d_out;            // [T][I]
    float* resid_out = out + (size_t)T * I;      // [T][H]
    uint8_t* q  = (uint8_t*)d_ws;                // q'  frag-tiles (T*H bytes)
    uint8_t* wt = q + (size_t)T * H;             // wt' frag-tiles (I*H bytes)

    // 1. weight convert + transpose -> fragment tiles
    wconv_kernel<<<dim3(I / 64, H / 64), 256, 0, stream>>>(w, wt, H, I);
    // 2. fused add + RMSNorm + static fp8 quant -> fragment tiles
    norm_quant_kernel<<<T, 256, 0, stream>>>(hs, res, nw, scale, resid_out, q, H);
    // 3. MX-fp8 GEMM + dequant (256x256 tiles, 4 waves, 16-MFMA ILP)
    gemm_fp8_kernel<<<(T / 256) * (I / 256), 256, 0, stream>>>(
        q, wt, out, scale, wscale, T, I, H);
}

// Round 7
// 505.721 us; speedup vs baseline: 1.2327x; 1.1060x over previous
//
#include <hip/hip_runtime.h>
#include <stdint.h>

// ---------------------------------------------------------------------------
// Fused: (add+RMSNorm+static fp8 quant) -> MX-fp8 GEMM (scale=1.0) -> dequant
// T=8192, H=4096, I=8192 (derived from in_sizes at launch)
// d_out = [ out f32 [T][I] | residual_out f32 [T][H] ]
// d_ws  = [ q' fp8 frag-tiles | wt' fp8 frag-tiles ]
//
// Fragment-tile layout (both operands; tile = 128 rows x 64 k-bytes = 8 KB):
//   tile_idx = (row>>7)*(K/64) + (k>>6)
//   chunk c  = s*4 + kc*2 + p   (s=(row>>5)&3, kc=(k>>5)&1, p=(k>>4)&1)
//   offset   = tile_idx*8192 + c*512 + (row&31)*16 + (k&15)
//
// GEMM (R7): 256x256 block tile, 8 waves (2Mx4N, wave tile 128x64).
// KEY CHANGE vs R3-R6: B operand NEVER touches LDS — B-frags are loaded
// global->VGPR (two coalesced 512B segments per frag), ping-pong buffered,
// depth-1 prefetch. Only A is staged via global_load_lds (3-slot, 48 KB).
// Rationale (measured): mfma_scale 32x32x64 demands 238 B/cyc/CU of operand
// reads at full rate vs ~85-128 B/cyc LDS sustained -> every all-LDS variant
// capped at ~35% MfmaUtil (R3/R4/R5/R6 all ~1620-1660 TF). Halving LDS bytes
// (A-only: ~940 cyc/tranche < 1100 cyc MFMA) removes LDS as binding pipe.
// vmcnt ledger (FIFO per iter): issue order A-stage(kt+2)[2], B(kt+1)[4];
// compiler's auto-wait for B(kt) use = vmcnt(6) -> counted discipline, never
// drains to 0. Manual vmcnt(6) at iter top is a structural no-op safety net
// guaranteeing A(kt)'s slot landed. Slot hazard: writes at iter kt target
// slot (kt+2)%3, mod-3 distinct from read slots kt%3/(kt+1)%3; per-iter
// barrier bounds wave drift to <1 iter.
// ---------------------------------------------------------------------------

typedef float float16v __attribute__((ext_vector_type(16)));
typedef int   int8v    __attribute__((ext_vector_type(8)));

#define GLOAD_LDS16(gp, lp)                                                    \
    __builtin_amdgcn_global_load_lds(                                          \
        (const __attribute__((address_space(1))) void*)(gp),                   \
        (__attribute__((address_space(3))) void*)(lp), 16, 0, 0)

#define MFMA_SCALE1(a, b, c)                                                   \
    __builtin_amdgcn_mfma_scale_f32_32x32x64_f8f6f4(                           \
        (a), (b), (c), 0, 0, 0, 0x7f7f7f7f, 0, 0x7f7f7f7f)

// ---------------------------------------------------------------------------
// Kernel 1: w f32 [K][N] -> fp8 fragment-tiles wt' (transpose: rows = n)
// ---------------------------------------------------------------------------
__global__ void __launch_bounds__(256) wconv_kernel(
    const float* __restrict__ w, uint8_t* __restrict__ wt, int K, int N) {
    __shared__ uint8_t tile[64 * 64];  // [n_local][k_local]
    const int k0 = blockIdx.y * 64;
    const int n0 = blockIdx.x * 64;
    const int t = threadIdx.x;
    const int c4 = t & 15;   // n-chunk of 4 floats
    const int r = t >> 4;    // k row base (0..15)

#pragma unroll
    for (int p = 0; p < 4; ++p) {
        const int k = r + p * 16;
        const float4 v = *(const float4*)(w + (size_t)(k0 + k) * N + n0 + c4 * 4);
        const int pk0 = __builtin_amdgcn_cvt_pk_fp8_f32(v.x, v.y, 0, false);
        const int pk1 = __builtin_amdgcn_cvt_pk_fp8_f32(v.z, v.w, 0, false);
        tile[(c4 * 4 + 0) * 64 + k] = (uint8_t)(pk0 & 0xff);
        tile[(c4 * 4 + 1) * 64 + k] = (uint8_t)((pk0 >> 8) & 0xff);
        tile[(c4 * 4 + 2) * 64 + k] = (uint8_t)(pk1 & 0xff);
        tile[(c4 * 4 + 3) * 64 + k] = (uint8_t)((pk1 >> 8) & 0xff);
    }
    __syncthreads();
    const int n_local = t >> 2;
    const int ch = t & 3;   // 16B piece within 64B k-group: c = s*4 + ch
    const uint4 val = *(const uint4*)(&tile[n_local * 64 + ch * 16]);
    const int n = n0 + n_local;
    const size_t tile_idx = (size_t)(n >> 7) * (K >> 6) + (k0 >> 6);
    const int c = ((n >> 5) & 3) * 4 + ch;
    *(uint4*)(wt + tile_idx * 8192 + c * 512 + (n & 31) * 16) = val;
}

// ---------------------------------------------------------------------------
// Kernel 2: residual_out = hs + res; RMSNorm; q' = fp8(norm/scale) frag-tiles
// ---------------------------------------------------------------------------
__global__ void __launch_bounds__(256) norm_quant_kernel(
    const float* __restrict__ hs, const float* __restrict__ res,
    const float* __restrict__ nw, const float* __restrict__ scale,
    float* __restrict__ resid_out, uint8_t* __restrict__ q, int H) {
    __shared__ float sm[4096];
    __shared__ float wsum[4];
    __shared__ float s_inv;
    const int row = blockIdx.x;
    const int t = threadIdx.x;
    const float* hrow = hs + (size_t)row * H;
    const float* rrow = res + (size_t)row * H;
    float* orow = resid_out + (size_t)row * H;

    float acc = 0.f;
#pragma unroll
    for (int p = 0; p < 4; ++p) {
        const int c = p * 1024 + t * 4;
        const float4 h = *(const float4*)(hrow + c);
        const float4 r = *(const float4*)(rrow + c);
        float4 s;
        s.x = h.x + r.x; s.y = h.y + r.y; s.z = h.z + r.z; s.w = h.w + r.w;
        *(float4*)(orow + c) = s;
        *(float4*)(&sm[c]) = s;
        acc += s.x * s.x + s.y * s.y + s.z * s.z + s.w * s.w;
    }
#pragma unroll
    for (int off = 32; off; off >>= 1) acc += __shfl_down(acc, off);
    if ((t & 63) == 0) wsum[t >> 6] = acc;
    __syncthreads();
    if (t == 0) {
        const float tot = wsum[0] + wsum[1] + wsum[2] + wsum[3];
        s_inv = 1.0f / sqrtf(tot / (float)H + 1e-6f);
    }
    __syncthreads();
    const float inv = s_inv;
    const float sval = scale[0];

    // pass 2: thread t quantizes elements [t*16, t*16+16)
    const int k0 = t * 16;
    uint32_t words[4];
#pragma unroll
    for (int i = 0; i < 4; ++i) {
        const float4 s = *(const float4*)(&sm[k0 + i * 4]);
        const float4 wv = *(const float4*)(nw + k0 + i * 4);
        float q0 = (s.x * inv * wv.x) / sval;
        float q1 = (s.y * inv * wv.y) / sval;
        float q2 = (s.z * inv * wv.z) / sval;
        float q3 = (s.w * inv * wv.w) / sval;
        q0 = fminf(fmaxf(q0, -448.f), 448.f);
        q1 = fminf(fmaxf(q1, -448.f), 448.f);
        q2 = fminf(fmaxf(q2, -448.f), 448.f);
        q3 = fminf(fmaxf(q3, -448.f), 448.f);
        int pk = __builtin_amdgcn_cvt_pk_fp8_f32(q0, q1, 0, false);
        pk = __builtin_amdgcn_cvt_pk_fp8_f32(q2, q3, pk, true);
        words[i] = (uint32_t)pk;
    }
    const int kt = t >> 2;           // k-tile (64B groups)
    const int ch = t & 3;            // 16B piece
    const size_t tile_idx = (size_t)(row >> 7) * (H >> 6) + kt;
    const int c = ((row >> 5) & 3) * 4 + ch;
    uint4 val;
    val.x = words[0]; val.y = words[1]; val.z = words[2]; val.w = words[3];
    *(uint4*)(q + tile_idx * 8192 + c * 512 + (row & 31) * 16) = val;
}

// ---------------------------------------------------------------------------
// helpers: 32-byte MFMA operand frag from LDS / from global
// ---------------------------------------------------------------------------
static __device__ __forceinline__ int8v ldfrag(const uint8_t* p) {
    const uint4 lo = *(const uint4*)p;
    const uint4 hi = *(const uint4*)(p + 512);
    int8v r = {(int)lo.x, (int)lo.y, (int)lo.z, (int)lo.w,
               (int)hi.x, (int)hi.y, (int)hi.z, (int)hi.w};
    return r;
}

// ---------------------------------------------------------------------------
// Kernel 3: MX-fp8 GEMM  C[M][N] = (A[M][K] @ B[N][K]^T) * (scale*wscale)
// 256x256 tile, 8 waves (2Mx4N, wave tile 128x64). A via LDS (3-slot),
// B direct global->VGPR ping-pong.
// ---------------------------------------------------------------------------
__global__ void __launch_bounds__(512, 2) gemm_fp8_kernel(
    const uint8_t* __restrict__ A,   // q'  frag-tiles
    const uint8_t* __restrict__ B,   // wt' frag-tiles
    float* __restrict__ C,           // out [M][N]
    const float* __restrict__ scale, const float* __restrict__ wscale,
    int M, int N, int K) {
    // 3 slots x 16 KB (A tranche image: rows 0-127 at 0, rows 128-255 at 8K)
    __shared__ uint8_t lds[3 * 16384];

    const int t = threadIdx.x;       // 0..511
    const int wid = t >> 6;          // 0..7
    const int lane = t & 63;
    const int wr = wid >> 2;         // 0..1  (M)
    const int wc = wid & 3;          // 0..3  (N)

    // XCD-bijective swizzle (gridDim.x == 1024, %8 == 0)
    const int id = blockIdx.x;
    const int wg = (id & 7) * ((int)gridDim.x >> 3) + (id >> 3);
    const int nbn = N >> 8;
    const int bm = wg / nbn;
    const int bn = wg % nbn;

    const int nkt = K >> 6;          // 64 tranches of 64 fp8 k-bytes
    const uint8_t* a0s = A + (size_t)(2 * bm) * nkt * 8192;      // rows 0-127
    const uint8_t* a1s = a0s + (size_t)nkt * 8192;               // rows 128-255
    const uint8_t* b0s = B + (size_t)(2 * bn) * nkt * 8192;      // cols 0-127
    const uint8_t* b1s = b0s + (size_t)nkt * 8192;               // cols 128-255
    const int o16 = t * 16;          // 512 threads x 16B = one 8KB tile image

    const int lgrp = (lane >> 5) * 1024;
    const int lrow = (lane & 31) * 16;

    // A frag offsets within a 16 KB slot (4 row-blocks of wave wr)
    int aoff[4];
#pragma unroll
    for (int mb = 0; mb < 4; ++mb) {
        const int r32 = wr * 4 + mb;
        aoff[mb] = (r32 >> 2) * 8192 + (r32 & 3) * 2048 + lgrp + lrow;
    }
    // B frag global base offsets (within a tranche image) for this wave's cols
    const uint8_t* bsrc[2];
    int bofs[2];
#pragma unroll
    for (int nb = 0; nb < 2; ++nb) {
        const int c32 = wc * 2 + nb;
        bsrc[nb] = (c32 & 4) ? b1s : b0s;
        bofs[nb] = (c32 & 3) * 2048 + lgrp + lrow;
    }

    float16v acc[4][2] = {};

#define STAGE_A(u, slot)                                                       \
    {                                                                          \
        const size_t _o = (size_t)(u) * 8192 + o16;                            \
        uint8_t* _d = lds + (slot) * 16384;                                    \
        GLOAD_LDS16(a0s + _o, _d + o16);                                       \
        GLOAD_LDS16(a1s + _o, _d + 8192 + o16);                                \
    }

#define LOAD_B(u, dst)                                                         \
    {                                                                          \
        const size_t _b = (size_t)(u) * 8192;                                  \
        dst[0] = ldfrag(bsrc[0] + _b + bofs[0]);                               \
        dst[1] = ldfrag(bsrc[1] + _b + bofs[1]);                               \
    }

#define DO_MFMA(slot, breg)                                                    \
    {                                                                          \
        const uint8_t* _s = lds + (slot) * 16384;                              \
        int8v _a[4];                                                           \
        _Pragma("unroll") for (int mb = 0; mb < 4; ++mb)                       \
            _a[mb] = ldfrag(_s + aoff[mb]);                                    \
        _Pragma("unroll") for (int mb = 0; mb < 4; ++mb) {                     \
            acc[mb][0] = MFMA_SCALE1(_a[mb], breg[0], acc[mb][0]);             \
            acc[mb][1] = MFMA_SCALE1(_a[mb], breg[1], acc[mb][1]);             \
        }                                                                      \
    }

    int8v b_even[2], b_odd[2];

    // prologue: A tranches 0,1 -> slots 0,1; B(0) -> b_even
    STAGE_A(0, 0)
    STAGE_A(1, 1)
    LOAD_B(0, b_even)

    // main loop, unrolled x2 for B ping-pong (nkt = 64, even)
    for (int kt = 0; kt < nkt; kt += 2) {
        const int s0 = kt % 3, s1 = (kt + 1) % 3, s2 = (kt + 2) % 3;
        // ---- even tranche kt: use b_even, prefetch B(kt+1) ----
        asm volatile("s_waitcnt vmcnt(6)" ::: "memory");
        __builtin_amdgcn_s_barrier();
        {
            const int pf = (kt + 2 < nkt) ? (kt + 2) : (nkt - 1);
            STAGE_A(pf, s2)
            const int bu = (kt + 1 < nkt) ? (kt + 1) : (nkt - 1);
            LOAD_B(bu, b_odd)
            DO_MFMA(s0, b_even)
        }
        // ---- odd tranche kt+1: use b_odd, prefetch B(kt+2) ----
        asm volatile("s_waitcnt vmcnt(6)" ::: "memory");
        __builtin_amdgcn_s_barrier();
        {
            const int pf = (kt + 3 < nkt) ? (kt + 3) : (nkt - 1);
            STAGE_A(pf, s0)
            const int bu = (kt + 2 < nkt) ? (kt + 2) : (nkt - 1);
            LOAD_B(bu, b_even)
            DO_MFMA(s1, b_odd)
        }
    }
#undef STAGE_A
#undef LOAD_B
#undef DO_MFMA

    // epilogue: C/D 32x32 layout col=lane&31, row=(reg&3)+8*(reg>>2)+4*(lane>>5)
    const float f = scale[0] * wscale[0];
    const int col = lane & 31;
    const int rb4 = (lane >> 5) * 4;
#pragma unroll
    for (int mb = 0; mb < 4; ++mb) {
#pragma unroll
        for (int nb = 0; nb < 2; ++nb) {
#pragma unroll
            for (int reg = 0; reg < 16; ++reg) {
                const int r = (reg & 3) + 8 * (reg >> 2) + rb4;
                const size_t gr = (size_t)(bm * 256 + wr * 128 + mb * 32 + r);
                const size_t gc = (size_t)(bn * 256 + wc * 64 + nb * 32 + col);
                C[gr * N + gc] = acc[mb][nb][reg] * f;
            }
        }
    }
}

// ---------------------------------------------------------------------------
extern "C" void kernel_launch(void* const* d_in, const int* in_sizes, int n_in,
                              void* d_out, int out_size, void* d_ws, size_t ws_size,
                              hipStream_t stream) {
    const float* hs     = (const float*)d_in[0];
    const float* res    = (const float*)d_in[1];
    const float* nw     = (const float*)d_in[2];
    const float* w      = (const float*)d_in[3];
    const float* scale  = (const float*)d_in[4];
    const float* wscale = (const float*)d_in[5];

    const int H = in_sizes[2];
    const int T = in_sizes[0] / H;
    const int I = in_sizes[3] / H;

    float* out       = (float*)d_out;            // [T][I]
    float* resid_out = out + (size_t)T * I;      // [T][H]
    uint8_t* q  = (uint8_t*)d_ws;                // q'  frag-tiles (T*H bytes)
    uint8_t* wt = q + (size_t)T * H;             // wt' frag-tiles (I*H bytes)

    // 1. weight convert + transpose -> fragment tiles
    wconv_kernel<<<dim3(I / 64, H / 64), 256, 0, stream>>>(w, wt, H, I);
    // 2. fused add + RMSNorm + static fp8 quant -> fragment tiles
    norm_quant_kernel<<<T, 256, 0, stream>>>(hs, res, nw, scale, resid_out, q, H);
    // 3. MX-fp8 GEMM + dequant (256x256, A via LDS, B direct-to-reg)
    gemm_fp8_kernel<<<(T / 256) * (I / 256), 512, 0, stream>>>(
        q, wt, out, scale, wscale, T, I, H);
}

// Round 8
// 485.091 us; speedup vs baseline: 1.2851x; 1.0425x over previous
//
#include <hip/hip_runtime.h>
#include <stdint.h>

// ---------------------------------------------------------------------------
// Fused: (add+RMSNorm+static fp8 quant) -> MX-fp8 GEMM (scale=1.0) -> dequant
// T=8192, H=4096, I=8192 (derived from in_sizes at launch)
// d_out = [ out f32 [T][I] | residual_out f32 [T][H] ]
// d_ws  = [ q' fp8 frag-tiles | wt' fp8 frag-tiles ]
//
// Fragment-tile layout (both operands; tile = 128 rows x 64 k-bytes = 8 KB):
//   tile_idx = (row>>7)*(K/64) + (k>>6)
//   chunk c  = s*4 + kc*2 + p   (s=(row>>5)&3, kc=(k>>5)&1, p=(k>>4)&1)
//   offset   = tile_idx*8192 + c*512 + (row&31)*16 + (k&15)
// Frag reads are lane-linear ds_read_b128 (measured 0 bank conflicts R3-R7).
//
// GEMM (R8): 256x128 block tile, 4 waves (2Mx2N, wave tile 128x64),
// 256 threads, LDS 3-slot x 24 KB = 72 KB -> TWO independent blocks/CU
// (the m97/m114 mechanism: cross-block overlap fills barrier bubbles).
// NO sched_barrier, NO setprio: R4-R7 all pinned the schedule and landed at
// 24-35% MfmaUtil; m141 showed order-pinning defeats the compiler's own
// fine-grained lgkmcnt interleave of ds_read with MFMA. Counted vmcnt(6) +
// one s_barrier per tranche; prefetch depth 2.
// vmcnt ledger: prologue stages tranches 0,1 (12 outstanding). At iter kt the
// wait vmcnt(6) drains exactly stage(kt); stage(kt+1)'s 6 stay in flight.
// Slot hazard: writes at kt target slot (kt+2)%3 = (kt-1)%3 whose readers
// finished before this barrier; junk tail-writes land in slots mod-3 distinct
// from remaining read slots.
// ---------------------------------------------------------------------------

typedef float float16v __attribute__((ext_vector_type(16)));
typedef int   int8v    __attribute__((ext_vector_type(8)));

#define GLOAD_LDS16(gp, lp)                                                    \
    __builtin_amdgcn_global_load_lds(                                          \
        (const __attribute__((address_space(1))) void*)(gp),                   \
        (__attribute__((address_space(3))) void*)(lp), 16, 0, 0)

#define MFMA_SCALE1(a, b, c)                                                   \
    __builtin_amdgcn_mfma_scale_f32_32x32x64_f8f6f4(                           \
        (a), (b), (c), 0, 0, 0, 0x7f7f7f7f, 0, 0x7f7f7f7f)

// ---------------------------------------------------------------------------
// Kernel 1: w f32 [K][N] -> fp8 fragment-tiles wt' (transpose: rows = n)
// ---------------------------------------------------------------------------
__global__ void __launch_bounds__(256) wconv_kernel(
    const float* __restrict__ w, uint8_t* __restrict__ wt, int K, int N) {
    __shared__ uint8_t tile[64 * 64];  // [n_local][k_local]
    const int k0 = blockIdx.y * 64;
    const int n0 = blockIdx.x * 64;
    const int t = threadIdx.x;
    const int c4 = t & 15;   // n-chunk of 4 floats
    const int r = t >> 4;    // k row base (0..15)

#pragma unroll
    for (int p = 0; p < 4; ++p) {
        const int k = r + p * 16;
        const float4 v = *(const float4*)(w + (size_t)(k0 + k) * N + n0 + c4 * 4);
        const int pk0 = __builtin_amdgcn_cvt_pk_fp8_f32(v.x, v.y, 0, false);
        const int pk1 = __builtin_amdgcn_cvt_pk_fp8_f32(v.z, v.w, 0, false);
        tile[(c4 * 4 + 0) * 64 + k] = (uint8_t)(pk0 & 0xff);
        tile[(c4 * 4 + 1) * 64 + k] = (uint8_t)((pk0 >> 8) & 0xff);
        tile[(c4 * 4 + 2) * 64 + k] = (uint8_t)(pk1 & 0xff);
        tile[(c4 * 4 + 3) * 64 + k] = (uint8_t)((pk1 >> 8) & 0xff);
    }
    __syncthreads();
    const int n_local = t >> 2;
    const int ch = t & 3;   // 16B piece within 64B k-group: c = s*4 + ch
    const uint4 val = *(const uint4*)(&tile[n_local * 64 + ch * 16]);
    const int n = n0 + n_local;
    const size_t tile_idx = (size_t)(n >> 7) * (K >> 6) + (k0 >> 6);
    const int c = ((n >> 5) & 3) * 4 + ch;
    *(uint4*)(wt + tile_idx * 8192 + c * 512 + (n & 31) * 16) = val;
}

// ---------------------------------------------------------------------------
// Kernel 2: residual_out = hs + res; RMSNorm; q' = fp8(norm/scale) frag-tiles
// ---------------------------------------------------------------------------
__global__ void __launch_bounds__(256) norm_quant_kernel(
    const float* __restrict__ hs, const float* __restrict__ res,
    const float* __restrict__ nw, const float* __restrict__ scale,
    float* __restrict__ resid_out, uint8_t* __restrict__ q, int H) {
    __shared__ float sm[4096];
    __shared__ float wsum[4];
    __shared__ float s_inv;
    const int row = blockIdx.x;
    const int t = threadIdx.x;
    const float* hrow = hs + (size_t)row * H;
    const float* rrow = res + (size_t)row * H;
    float* orow = resid_out + (size_t)row * H;

    float acc = 0.f;
#pragma unroll
    for (int p = 0; p < 4; ++p) {
        const int c = p * 1024 + t * 4;
        const float4 h = *(const float4*)(hrow + c);
        const float4 r = *(const float4*)(rrow + c);
        float4 s;
        s.x = h.x + r.x; s.y = h.y + r.y; s.z = h.z + r.z; s.w = h.w + r.w;
        *(float4*)(orow + c) = s;
        *(float4*)(&sm[c]) = s;
        acc += s.x * s.x + s.y * s.y + s.z * s.z + s.w * s.w;
    }
#pragma unroll
    for (int off = 32; off; off >>= 1) acc += __shfl_down(acc, off);
    if ((t & 63) == 0) wsum[t >> 6] = acc;
    __syncthreads();
    if (t == 0) {
        const float tot = wsum[0] + wsum[1] + wsum[2] + wsum[3];
        s_inv = 1.0f / sqrtf(tot / (float)H + 1e-6f);
    }
    __syncthreads();
    const float inv = s_inv;
    const float sval = scale[0];

    // pass 2: thread t quantizes elements [t*16, t*16+16)
    const int k0 = t * 16;
    uint32_t words[4];
#pragma unroll
    for (int i = 0; i < 4; ++i) {
        const float4 s = *(const float4*)(&sm[k0 + i * 4]);
        const float4 wv = *(const float4*)(nw + k0 + i * 4);
        float q0 = (s.x * inv * wv.x) / sval;
        float q1 = (s.y * inv * wv.y) / sval;
        float q2 = (s.z * inv * wv.z) / sval;
        float q3 = (s.w * inv * wv.w) / sval;
        q0 = fminf(fmaxf(q0, -448.f), 448.f);
        q1 = fminf(fmaxf(q1, -448.f), 448.f);
        q2 = fminf(fmaxf(q2, -448.f), 448.f);
        q3 = fminf(fmaxf(q3, -448.f), 448.f);
        int pk = __builtin_amdgcn_cvt_pk_fp8_f32(q0, q1, 0, false);
        pk = __builtin_amdgcn_cvt_pk_fp8_f32(q2, q3, pk, true);
        words[i] = (uint32_t)pk;
    }
    const int kt = t >> 2;           // k-tile (64B groups)
    const int ch = t & 3;            // 16B piece
    const size_t tile_idx = (size_t)(row >> 7) * (H >> 6) + kt;
    const int c = ((row >> 5) & 3) * 4 + ch;
    uint4 val;
    val.x = words[0]; val.y = words[1]; val.z = words[2]; val.w = words[3];
    *(uint4*)(q + tile_idx * 8192 + c * 512 + (row & 31) * 16) = val;
}

// ---------------------------------------------------------------------------
// helper: load one 32-byte MFMA operand frag from a 2KB frag sub-block
// ---------------------------------------------------------------------------
static __device__ __forceinline__ int8v ldfrag(const uint8_t* p) {
    const uint4 lo = *(const uint4*)p;
    const uint4 hi = *(const uint4*)(p + 512);
    int8v r = {(int)lo.x, (int)lo.y, (int)lo.z, (int)lo.w,
               (int)hi.x, (int)hi.y, (int)hi.z, (int)hi.w};
    return r;
}

// ---------------------------------------------------------------------------
// Kernel 3: MX-fp8 GEMM  C[M][N] = (A[M][K] @ B[N][K]^T) * (scale*wscale)
// 256x128 tile, 4 waves (2x2, wave tile 128x64), compiler-scheduled body,
// 2 blocks/CU, counted vmcnt, 1 barrier/tranche.
// ---------------------------------------------------------------------------
__global__ void __launch_bounds__(256, 2) gemm_fp8_kernel(
    const uint8_t* __restrict__ A,   // q'  frag-tiles
    const uint8_t* __restrict__ B,   // wt' frag-tiles
    float* __restrict__ C,           // out [M][N]
    const float* __restrict__ scale, const float* __restrict__ wscale,
    int M, int N, int K) {
    // 3 slots x 24 KB: slot = A rows0-127 (8K) | A rows128-255 (8K) | B (8K)
    __shared__ uint8_t lds[3 * 24576];

    const int t = threadIdx.x;       // 0..255
    const int wid = t >> 6;          // 0..3
    const int lane = t & 63;
    const int wr = wid >> 1;         // 0..1  (M)
    const int wc = wid & 1;          // 0..1  (N)

    // XCD-bijective swizzle (gridDim.x == 2048, %8 == 0)
    const int id = blockIdx.x;
    const int wg = (id & 7) * ((int)gridDim.x >> 3) + (id >> 3);
    const int nbn = N >> 7;
    const int bm = wg / nbn;
    const int bn = wg % nbn;

    const int nkt = K >> 6;          // 64 tranches of 64 fp8 k-bytes
    const uint8_t* a0s = A + (size_t)(2 * bm) * nkt * 8192;   // rows 0-127
    const uint8_t* a1s = a0s + (size_t)nkt * 8192;            // rows 128-255
    const uint8_t* bs  = B + (size_t)bn * nkt * 8192;         // cols 0-127
    const int o16 = t * 16;          // [0, 4096): 256 threads x 16B per gload

    const int lgrp = (lane >> 5) * 1024;
    const int lrow = (lane & 31) * 16;
    const int abase = wr * 8192 + lgrp + lrow;            // wave's A image
    const int bbase = 16384 + wc * 4096 + lgrp + lrow;    // wave's B cols

    float16v acc[4][2] = {};

#define STAGE(u, slot)                                                         \
    {                                                                          \
        const size_t _o = (size_t)(u) * 8192 + o16;                            \
        uint8_t* _d = lds + (slot) * 24576;                                    \
        GLOAD_LDS16(a0s + _o,        _d + o16);                                \
        GLOAD_LDS16(a0s + _o + 4096, _d + 4096 + o16);                         \
        GLOAD_LDS16(a1s + _o,        _d + 8192 + o16);                         \
        GLOAD_LDS16(a1s + _o + 4096, _d + 12288 + o16);                        \
        GLOAD_LDS16(bs + _o,         _d + 16384 + o16);                        \
        GLOAD_LDS16(bs + _o + 4096,  _d + 20480 + o16);                        \
    }

    // prologue: stage tranches 0,1 into slots 0,1 (12 outstanding)
    STAGE(0, 0)
    STAGE(1, 1)

    int cur = 0, pfs = 2;
    for (int kt = 0; kt < nkt; ++kt) {
        // drain exactly stage(kt); stage(kt+1) stays in flight
        asm volatile("s_waitcnt vmcnt(6)" ::: "memory");
        __builtin_amdgcn_s_barrier();

        // prefetch tranche kt+2 (tail-clamped; junk slot mod-3 distinct)
        const int pf = (kt + 2 < nkt) ? (kt + 2) : (nkt - 1);
        STAGE(pf, pfs)

        // compiler-scheduled reads + MFMAs (no pins)
        const uint8_t* sl = lds + cur * 24576;
        int8v a[4], b[2];
#pragma unroll
        for (int mb = 0; mb < 4; ++mb) a[mb] = ldfrag(sl + abase + mb * 2048);
#pragma unroll
        for (int nb = 0; nb < 2; ++nb) b[nb] = ldfrag(sl + bbase + nb * 2048);
#pragma unroll
        for (int mb = 0; mb < 4; ++mb)
#pragma unroll
            for (int nb = 0; nb < 2; ++nb)
                acc[mb][nb] = MFMA_SCALE1(a[mb], b[nb], acc[mb][nb]);

        cur = (cur == 2) ? 0 : cur + 1;
        pfs = (pfs == 2) ? 0 : pfs + 1;
    }
#undef STAGE

    // epilogue: C/D 32x32 layout col=lane&31, row=(reg&3)+8*(reg>>2)+4*(lane>>5)
    const float f = scale[0] * wscale[0];
    const int col = lane & 31;
    const int rb4 = (lane >> 5) * 4;
#pragma unroll
    for (int mb = 0; mb < 4; ++mb) {
#pragma unroll
        for (int nb = 0; nb < 2; ++nb) {
#pragma unroll
            for (int reg = 0; reg < 16; ++reg) {
                const int r = (reg & 3) + 8 * (reg >> 2) + rb4;
                const size_t gr = (size_t)(bm * 256 + wr * 128 + mb * 32 + r);
                const size_t gc = (size_t)(bn * 128 + wc * 64 + nb * 32 + col);
                C[gr * N + gc] = acc[mb][nb][reg] * f;
            }
        }
    }
}

// ---------------------------------------------------------------------------
extern "C" void kernel_launch(void* const* d_in, const int* in_sizes, int n_in,
                              void* d_out, int out_size, void* d_ws, size_t ws_size,
                              hipStream_t stream) {
    const float* hs     = (const float*)d_in[0];
    const float* res    = (const float*)d_in[1];
    const float* nw     = (const float*)d_in[2];
    const float* w      = (const float*)d_in[3];
    const float* scale  = (const float*)d_in[4];
    const float* wscale = (const float*)d_in[5];

    const int H = in_sizes[2];
    const int T = in_sizes[0] / H;
    const int I = in_sizes[3] / H;

    float* out       = (float*)d_out;            // [T][I]
    float* resid_out = out + (size_t)T * I;      // [T][H]
    uint8_t* q  = (uint8_t*)d_ws;                // q'  frag-tiles (T*H bytes)
    uint8_t* wt = q + (size_t)T * H;             // wt' frag-tiles (I*H bytes)

    // 1. weight convert + transpose -> fragment tiles
    wconv_kernel<<<dim3(I / 64, H / 64), 256, 0, stream>>>(w, wt, H, I);
    // 2. fused add + RMSNorm + static fp8 quant -> fragment tiles
    norm_quant_kernel<<<T, 256, 0, stream>>>(hs, res, nw, scale, resid_out, q, H);
    // 3. MX-fp8 GEMM + dequant (256x128 tiles, 2 blocks/CU, unpinned body)
    gemm_fp8_kernel<<<(T / 256) * (I / 128), 256, 0, stream>>>(
        q, wt, out, scale, wscale, T, I, H);
}

// Round 10
// 401.783 us; speedup vs baseline: 1.5516x; 1.2073x over previous
//
#include <hip/hip_runtime.h>
#include <stdint.h>

// ---------------------------------------------------------------------------
// Fused: (add+RMSNorm+static fp8 quant) -> MX-fp8 GEMM (scale=1.0) -> dequant
// T=8192, H=4096, I=8192 (derived from in_sizes at launch)
// d_out = [ out f32 [T][I] | residual_out f32 [T][H] ]
// d_ws  = [ q' fp8 frag-tiles | wt' fp8 frag-tiles ]
//
// Fragment-tile layout (both operands; tile = 128 rows x 64 k-bytes = 8 KB):
//   tile_idx = (row>>7)*(K/64) + (k>>6)
//   chunk c  = s*4 + kc*2 + p   (s=(row>>5)&3, kc=(k>>5)&1, p=(k>>4)&1)
//   offset   = tile_idx*8192 + c*512 + (row&31)*16 + (k&15)
// Frag reads are lane-linear ds_read_b128 (measured 0 bank conflicts R3-R8).
//
// GEMM (R9/R10): BARRIER-LESS wave-private pipeline. 256 thr / 4 waves (2x2),
// wave tile 128x128, block tile 256x256. Each wave stages its OWN A-image
// (8 KB) + B-image (8 KB) into its OWN LDS region -> zero cross-wave LDS
// deps -> ZERO s_barrier in the K-loop. Waves free-run on counted vmcnt;
// register double-buffer (even/odd unroll, static indices) lets ds_reads of
// tranche t+1 hide under the 16-MFMA cluster of tranche t.
// Rationale: R3-R8 (5 schedule topologies, all block-cooperative staging +
// per-tranche barrier lockstep) all landed 24-35% MfmaUtil with NO saturated
// pipe (LDS 28 B/cyc, HBM <30%, MFMA 32%) -> the shared suspect is barrier
// lockstep itself. Cost accepted: 2x staging traffic (L3-resident) and
// 1 wave/SIMD (acc 256 + frag 128 VGPR).
// vmcnt ledger (per wave, 16 gloads/tranche): prologue stages t0,t1 (32 out);
// each half-iter: lgkmcnt(0) [own frag reads drained before overwriting that
// slot], stage next (->32 out), vmcnt(16) [drains the tranche about to be
// read], 16 ds_reads, 16 MFMAs. Tail clamps stage source; junk lands in a
// slot whose real data is already in registers. Never drains vmcnt to 0.
// R10 fix: __builtin_nontemporal_store needs a true vector type, not HIP's
// float4 class -> cast through ext_vector float4v.
// ---------------------------------------------------------------------------

typedef float float16v __attribute__((ext_vector_type(16)));
typedef float float4v  __attribute__((ext_vector_type(4)));
typedef int   int8v    __attribute__((ext_vector_type(8)));

#define GLOAD_LDS16(gp, lp)                                                    \
    __builtin_amdgcn_global_load_lds(                                          \
        (const __attribute__((address_space(1))) void*)(gp),                   \
        (__attribute__((address_space(3))) void*)(lp), 16, 0, 0)

#define MFMA_SCALE1(a, b, c)                                                   \
    __builtin_amdgcn_mfma_scale_f32_32x32x64_f8f6f4(                           \
        (a), (b), (c), 0, 0, 0, 0x7f7f7f7f, 0, 0x7f7f7f7f)

// ---------------------------------------------------------------------------
// Kernel 1: fused producer. Blocks [0, nwb) do weight convert+transpose;
// blocks [nwb, nwb+T) do add+RMSNorm+quant. residual_out uses nontemporal
// stores (write-once stream, keeps q/wt L3-resident for the GEMM).
// ---------------------------------------------------------------------------
__global__ void __launch_bounds__(256) prep_kernel(
    const float* __restrict__ w, uint8_t* __restrict__ wt,      // wconv part
    const float* __restrict__ hs, const float* __restrict__ res,
    const float* __restrict__ nw, const float* __restrict__ scale,
    float* __restrict__ resid_out, uint8_t* __restrict__ q,     // norm part
    int K, int N, int H, int nwb) {
    __shared__ float smemf[4104];
    const int t = threadIdx.x;

    if ((int)blockIdx.x < nwb) {
        // ---------------- wconv: w f32 [K][N] -> fp8 frag-tiles (rows = n)
        uint8_t* tile = (uint8_t*)smemf;  // 64x64
        const int nbx = N >> 6;
        const int k0 = ((int)blockIdx.x / nbx) * 64;
        const int n0 = ((int)blockIdx.x % nbx) * 64;
        const int c4 = t & 15;
        const int r = t >> 4;
#pragma unroll
        for (int p = 0; p < 4; ++p) {
            const int k = r + p * 16;
            const float4 v = *(const float4*)(w + (size_t)(k0 + k) * N + n0 + c4 * 4);
            const int pk0 = __builtin_amdgcn_cvt_pk_fp8_f32(v.x, v.y, 0, false);
            const int pk1 = __builtin_amdgcn_cvt_pk_fp8_f32(v.z, v.w, 0, false);
            tile[(c4 * 4 + 0) * 64 + k] = (uint8_t)(pk0 & 0xff);
            tile[(c4 * 4 + 1) * 64 + k] = (uint8_t)((pk0 >> 8) & 0xff);
            tile[(c4 * 4 + 2) * 64 + k] = (uint8_t)(pk1 & 0xff);
            tile[(c4 * 4 + 3) * 64 + k] = (uint8_t)((pk1 >> 8) & 0xff);
        }
        __syncthreads();
        const int n_local = t >> 2;
        const int ch = t & 3;
        const uint4 val = *(const uint4*)(&tile[n_local * 64 + ch * 16]);
        const int n = n0 + n_local;
        const size_t tile_idx = (size_t)(n >> 7) * (K >> 6) + (k0 >> 6);
        const int c = ((n >> 5) & 3) * 4 + ch;
        *(uint4*)(wt + tile_idx * 8192 + c * 512 + (n & 31) * 16) = val;
    } else {
        // ---------------- norm_quant: one block per row
        float* sm = smemf;
        float* wsum = smemf + 4096;
        const int row = (int)blockIdx.x - nwb;
        const float* hrow = hs + (size_t)row * H;
        const float* rrow = res + (size_t)row * H;
        float* orow = resid_out + (size_t)row * H;

        float acc = 0.f;
#pragma unroll
        for (int p = 0; p < 4; ++p) {
            const int c = p * 1024 + t * 4;
            const float4 h = *(const float4*)(hrow + c);
            const float4 r = *(const float4*)(rrow + c);
            float4v s;
            s.x = h.x + r.x; s.y = h.y + r.y; s.z = h.z + r.z; s.w = h.w + r.w;
            __builtin_nontemporal_store(s, (float4v*)(orow + c));
            *(float4v*)(&sm[c]) = s;
            acc += s.x * s.x + s.y * s.y + s.z * s.z + s.w * s.w;
        }
#pragma unroll
        for (int off = 32; off; off >>= 1) acc += __shfl_down(acc, off);
        if ((t & 63) == 0) wsum[t >> 6] = acc;
        __syncthreads();
        if (t == 0) {
            const float tot = wsum[0] + wsum[1] + wsum[2] + wsum[3];
            wsum[4] = 1.0f / sqrtf(tot / (float)H + 1e-6f);
        }
        __syncthreads();
        const float inv = wsum[4];
        const float sval = scale[0];

        const int k0 = t * 16;
        uint32_t words[4];
#pragma unroll
        for (int i = 0; i < 4; ++i) {
            const float4 s = *(const float4*)(&sm[k0 + i * 4]);
            const float4 wv = *(const float4*)(nw + k0 + i * 4);
            float q0 = (s.x * inv * wv.x) / sval;
            float q1 = (s.y * inv * wv.y) / sval;
            float q2 = (s.z * inv * wv.z) / sval;
            float q3 = (s.w * inv * wv.w) / sval;
            q0 = fminf(fmaxf(q0, -448.f), 448.f);
            q1 = fminf(fmaxf(q1, -448.f), 448.f);
            q2 = fminf(fmaxf(q2, -448.f), 448.f);
            q3 = fminf(fmaxf(q3, -448.f), 448.f);
            int pk = __builtin_amdgcn_cvt_pk_fp8_f32(q0, q1, 0, false);
            pk = __builtin_amdgcn_cvt_pk_fp8_f32(q2, q3, pk, true);
            words[i] = (uint32_t)pk;
        }
        const int kt = t >> 2;
        const int ch = t & 3;
        const size_t tile_idx = (size_t)(row >> 7) * (H >> 6) + kt;
        const int c = ((row >> 5) & 3) * 4 + ch;
        uint4 val;
        val.x = words[0]; val.y = words[1]; val.z = words[2]; val.w = words[3];
        *(uint4*)(q + tile_idx * 8192 + c * 512 + (row & 31) * 16) = val;
    }
}

// ---------------------------------------------------------------------------
// helper: load one 32-byte MFMA operand frag from a 2KB frag sub-block
// ---------------------------------------------------------------------------
static __device__ __forceinline__ int8v ldfrag(const uint8_t* p) {
    const uint4 lo = *(const uint4*)p;
    const uint4 hi = *(const uint4*)(p + 512);
    int8v r = {(int)lo.x, (int)lo.y, (int)lo.z, (int)lo.w,
               (int)hi.x, (int)hi.y, (int)hi.z, (int)hi.w};
    return r;
}

// ---------------------------------------------------------------------------
// Kernel 2: MX-fp8 GEMM, barrier-less wave-private pipeline (see header).
// ---------------------------------------------------------------------------
__global__ void __launch_bounds__(256, 1) gemm_fp8_kernel(
    const uint8_t* __restrict__ A,   // q'  frag-tiles
    const uint8_t* __restrict__ B,   // wt' frag-tiles
    float* __restrict__ C,           // out [M][N]
    const float* __restrict__ scale, const float* __restrict__ wscale,
    int M, int N, int K) {
    // 2 slots x (4 waves x 16 KB): wave region = A-image(8K) | B-image(8K)
    __shared__ uint8_t lds[2 * 65536];

    const int t = threadIdx.x;       // 0..255
    const int wid = t >> 6;          // 0..3
    const int lane = t & 63;
    const int wr = wid >> 1;         // 0..1  (M)
    const int wc = wid & 1;          // 0..1  (N)

    // XCD-bijective swizzle (gridDim.x == 1024, %8 == 0)
    const int id = blockIdx.x;
    const int wg = (id & 7) * ((int)gridDim.x >> 3) + (id >> 3);
    const int nbn = N >> 8;
    const int bm = wg / nbn;
    const int bn = wg % nbn;

    const int nkt = K >> 6;          // 64 tranches of 64 fp8 k-bytes
    // this wave's operand panels (wave tile 128x128)
    const uint8_t* aimg = A + (size_t)(2 * bm + wr) * nkt * 8192;
    const uint8_t* bimg = B + (size_t)(2 * bn + wc) * nkt * 8192;
    const int l16 = lane * 16;
    const int lgl = (lane >> 5) * 1024 + (lane & 31) * 16;

    uint8_t* wb0 = lds + wid * 16384;           // this wave, slot 0
    uint8_t* wb1 = lds + 65536 + wid * 16384;   // this wave, slot 1

    // 16 wave-private gloads: 8 for A image, 8 for B image
#define STAGEW(u, base)                                                        \
    {                                                                          \
        const size_t _o = (size_t)(u) * 8192;                                  \
        _Pragma("unroll") for (int c = 0; c < 8; ++c) {                        \
            GLOAD_LDS16(aimg + _o + c * 1024 + l16, (base) + c * 1024 + l16);  \
            GLOAD_LDS16(bimg + _o + c * 1024 + l16,                            \
                        (base) + 8192 + c * 1024 + l16);                       \
        }                                                                      \
    }

#define READF(base, fa, fb)                                                    \
    {                                                                          \
        _Pragma("unroll") for (int q = 0; q < 4; ++q) {                        \
            fa[q] = ldfrag((base) + q * 2048 + lgl);                           \
            fb[q] = ldfrag((base) + 8192 + q * 2048 + lgl);                    \
        }                                                                      \
    }

#define MFMA16(fa, fb)                                                         \
    {                                                                          \
        _Pragma("unroll") for (int mb = 0; mb < 4; ++mb)                       \
            _Pragma("unroll") for (int nb = 0; nb < 4; ++nb)                   \
                acc[mb][nb] = MFMA_SCALE1(fa[mb], fb[nb], acc[mb][nb]);        \
    }

    float16v acc[4][4] = {};
    int8v fAa[4], fAb[4], fBa[4], fBb[4];

    // prologue: stage tranches 0,1 (32 outstanding); read tranche 0 -> fA
    STAGEW(0, wb0)
    STAGEW(1, wb1)
    asm volatile("s_waitcnt vmcnt(16)" ::: "memory");   // tranche 0 landed
    READF(wb0, fAa, fAb)

    for (int kt = 0; kt < nkt; kt += 2) {
        // ---- even: MFMA tranche kt (fA); read kt+1 -> fB; stage kt+2 ----
        asm volatile("s_waitcnt lgkmcnt(0)" ::: "memory");  // slot0 reads done
        {
            const int u = (kt + 2 < nkt) ? (kt + 2) : (nkt - 1);
            STAGEW(u, wb0)
        }
        asm volatile("s_waitcnt vmcnt(16)" ::: "memory");   // tranche kt+1 in
        READF(wb1, fBa, fBb)
        MFMA16(fAa, fAb)
        // ---- odd: MFMA tranche kt+1 (fB); read kt+2 -> fA; stage kt+3 ----
        asm volatile("s_waitcnt lgkmcnt(0)" ::: "memory");  // slot1 reads done
        {
            const int u = (kt + 3 < nkt) ? (kt + 3) : (nkt - 1);
            STAGEW(u, wb1)
        }
        asm volatile("s_waitcnt vmcnt(16)" ::: "memory");   // tranche kt+2 in
        READF(wb0, fAa, fAb)
        MFMA16(fBa, fBb)
    }
#undef STAGEW
#undef READF
#undef MFMA16

    // epilogue: C/D 32x32 layout col=lane&31, row=(reg&3)+8*(reg>>2)+4*(lane>>5)
    // nontemporal: C is a write-once stream; keep q/wt resident in L3.
    const float f = scale[0] * wscale[0];
    const int col = lane & 31;
    const int rb4 = (lane >> 5) * 4;
#pragma unroll
    for (int mb = 0; mb < 4; ++mb) {
#pragma unroll
        for (int nb = 0; nb < 4; ++nb) {
#pragma unroll
            for (int reg = 0; reg < 16; ++reg) {
                const int r = (reg & 3) + 8 * (reg >> 2) + rb4;
                const size_t gr = (size_t)(bm * 256 + wr * 128 + mb * 32 + r);
                const size_t gc = (size_t)(bn * 256 + wc * 128 + nb * 32 + col);
                __builtin_nontemporal_store(acc[mb][nb][reg] * f, &C[gr * N + gc]);
            }
        }
    }
}

// ---------------------------------------------------------------------------
extern "C" void kernel_launch(void* const* d_in, const int* in_sizes, int n_in,
                              void* d_out, int out_size, void* d_ws, size_t ws_size,
                              hipStream_t stream) {
    const float* hs     = (const float*)d_in[0];
    const float* res    = (const float*)d_in[1];
    const float* nw     = (const float*)d_in[2];
    const float* w      = (const float*)d_in[3];
    const float* scale  = (const float*)d_in[4];
    const float* wscale = (const float*)d_in[5];

    const int H = in_sizes[2];
    const int T = in_sizes[0] / H;
    const int I = in_sizes[3] / H;

    float* out       = (float*)d_out;            // [T][I]
    float* resid_out = out + (size_t)T * I;      // [T][H]
    uint8_t* q  = (uint8_t*)d_ws;                // q'  frag-tiles (T*H bytes)
    uint8_t* wt = q + (size_t)T * H;             // wt' frag-tiles (I*H bytes)

    // 1. fused producers: wconv blocks + norm blocks in one launch
    const int nwb = (I / 64) * (H / 64);
    prep_kernel<<<nwb + T, 256, 0, stream>>>(
        w, wt, hs, res, nw, scale, resid_out, q, H, I, H, nwb);
    // 2. MX-fp8 GEMM + dequant (barrier-less wave-private pipeline)
    gemm_fp8_kernel<<<(T / 256) * (I / 256), 256, 0, stream>>>(
        q, wt, out, scale, wscale, T, I, H);
}

// Round 13
// 381.889 us; speedup vs baseline: 1.6324x; 1.0521x over previous
//
#include <hip/hip_runtime.h>
#include <stdint.h>

// ---------------------------------------------------------------------------
// Fused: (add+RMSNorm+static fp8 quant) -> MX-fp8 GEMM (scale=1.0) -> dequant
// T=8192, H=4096, I=8192 (derived from in_sizes at launch)
// d_out = [ out f32 [T][I] | residual_out f32 [T][H] ]
// d_ws  = [ q' fp8 frag-tiles | wt' fp8 frag-tiles ]
//
// Fragment-tile layout (both operands; tile = 128 rows x 64 k-bytes = 8 KB):
//   tile_idx = (row>>7)*(K/64) + (k>>6)
//   chunk c  = s*4 + kc*2 + p   (s=(row>>5)&3, kc=(k>>5)&1, p=(k>>4)&1)
//   offset   = tile_idx*8192 + c*512 + (row&31)*16 + (k&15)
// Frag reads are lane-linear ds_read_b128 (measured 0 bank conflicts R3-R10).
//
// GEMM: barrier-less wave-private pipeline (R10 structure, best measured
// = 336 us, 35.5% MfmaUtil — the empirical band edge for mfma_scale fed
// from memory on gfx950; invariant across 7 structure variants R3-R10).
// R11 changes (micro-polish, corpus-backed):
//  - XCD swizzle REMOVED: q+wt = 100 MB is L3-resident; m160 measured
//    swizzle costs ~2% in the L3-fit regime.
//  - prep uses nontemporal LOADS for hs/res/w (read-once streams, 536 MB)
//    to preserve L3 residency of q/wt for the GEMM.
// vmcnt ledger (per wave, 16 gloads/tranche): prologue stages t0,t1 (32 out);
// each half-iter: lgkmcnt(0) [own frag reads drained before overwriting that
// slot], stage next (->32 out), vmcnt(16) [drains the tranche about to be
// read], 16 ds_reads, 16 MFMAs. Tail clamps stage source; junk lands in a
// slot whose real data is already in registers. Never drains vmcnt to 0.
// ---------------------------------------------------------------------------

typedef float float16v __attribute__((ext_vector_type(16)));
typedef float float4v  __attribute__((ext_vector_type(4)));
typedef int   int8v    __attribute__((ext_vector_type(8)));

#define GLOAD_LDS16(gp, lp)                                                    \
    __builtin_amdgcn_global_load_lds(                                          \
        (const __attribute__((address_space(1))) void*)(gp),                   \
        (__attribute__((address_space(3))) void*)(lp), 16, 0, 0)

#define MFMA_SCALE1(a, b, c)                                                   \
    __builtin_amdgcn_mfma_scale_f32_32x32x64_f8f6f4(                           \
        (a), (b), (c), 0, 0, 0, 0x7f7f7f7f, 0, 0x7f7f7f7f)

// ---------------------------------------------------------------------------
// Kernel 1: fused producer. Blocks [0, nwb) do weight convert+transpose;
// blocks [nwb, nwb+T) do add+RMSNorm+quant. Read-once inputs use nontemporal
// loads; residual_out uses nontemporal stores (keep q/wt L3-resident).
// ---------------------------------------------------------------------------
__global__ void __launch_bounds__(256) prep_kernel(
    const float* __restrict__ w, uint8_t* __restrict__ wt,      // wconv part
    const float* __restrict__ hs, const float* __restrict__ res,
    const float* __restrict__ nw, const float* __restrict__ scale,
    float* __restrict__ resid_out, uint8_t* __restrict__ q,     // norm part
    int K, int N, int H, int nwb) {
    __shared__ float smemf[4104];
    const int t = threadIdx.x;

    if ((int)blockIdx.x < nwb) {
        // ---------------- wconv: w f32 [K][N] -> fp8 frag-tiles (rows = n)
        uint8_t* tile = (uint8_t*)smemf;  // 64x64
        const int nbx = N >> 6;
        const int k0 = ((int)blockIdx.x / nbx) * 64;
        const int n0 = ((int)blockIdx.x % nbx) * 64;
        const int c4 = t & 15;
        const int r = t >> 4;
#pragma unroll
        for (int p = 0; p < 4; ++p) {
            const int k = r + p * 16;
            const float4v v = __builtin_nontemporal_load(
                (const float4v*)(w + (size_t)(k0 + k) * N + n0 + c4 * 4));
            const int pk0 = __builtin_amdgcn_cvt_pk_fp8_f32(v.x, v.y, 0, false);
            const int pk1 = __builtin_amdgcn_cvt_pk_fp8_f32(v.z, v.w, 0, false);
            tile[(c4 * 4 + 0) * 64 + k] = (uint8_t)(pk0 & 0xff);
            tile[(c4 * 4 + 1) * 64 + k] = (uint8_t)((pk0 >> 8) & 0xff);
            tile[(c4 * 4 + 2) * 64 + k] = (uint8_t)(pk1 & 0xff);
            tile[(c4 * 4 + 3) * 64 + k] = (uint8_t)((pk1 >> 8) & 0xff);
        }
        __syncthreads();
        const int n_local = t >> 2;
        const int ch = t & 3;
        const uint4 val = *(const uint4*)(&tile[n_local * 64 + ch * 16]);
        const int n = n0 + n_local;
        const size_t tile_idx = (size_t)(n >> 7) * (K >> 6) + (k0 >> 6);
        const int c = ((n >> 5) & 3) * 4 + ch;
        *(uint4*)(wt + tile_idx * 8192 + c * 512 + (n & 31) * 16) = val;
    } else {
        // ---------------- norm_quant: one block per row
        float* sm = smemf;
        float* wsum = smemf + 4096;
        const int row = (int)blockIdx.x - nwb;
        const float* hrow = hs + (size_t)row * H;
        const float* rrow = res + (size_t)row * H;
        float* orow = resid_out + (size_t)row * H;

        float acc = 0.f;
#pragma unroll
        for (int p = 0; p < 4; ++p) {
            const int c = p * 1024 + t * 4;
            const float4v h = __builtin_nontemporal_load((const float4v*)(hrow + c));
            const float4v r = __builtin_nontemporal_load((const float4v*)(rrow + c));
            float4v s = h + r;
            __builtin_nontemporal_store(s, (float4v*)(orow + c));
            *(float4v*)(&sm[c]) = s;
            acc += s.x * s.x + s.y * s.y + s.z * s.z + s.w * s.w;
        }
#pragma unroll
        for (int off = 32; off; off >>= 1) acc += __shfl_down(acc, off);
        if ((t & 63) == 0) wsum[t >> 6] = acc;
        __syncthreads();
        if (t == 0) {
            const float tot = wsum[0] + wsum[1] + wsum[2] + wsum[3];
            wsum[4] = 1.0f / sqrtf(tot / (float)H + 1e-6f);
        }
        __syncthreads();
        const float inv = wsum[4];
        const float sval = scale[0];

        const int k0 = t * 16;
        uint32_t words[4];
#pragma unroll
        for (int i = 0; i < 4; ++i) {
            const float4 s = *(const float4*)(&sm[k0 + i * 4]);
            const float4 wv = *(const float4*)(nw + k0 + i * 4);
            float q0 = (s.x * inv * wv.x) / sval;
            float q1 = (s.y * inv * wv.y) / sval;
            float q2 = (s.z * inv * wv.z) / sval;
            float q3 = (s.w * inv * wv.w) / sval;
            q0 = fminf(fmaxf(q0, -448.f), 448.f);
            q1 = fminf(fmaxf(q1, -448.f), 448.f);
            q2 = fminf(fmaxf(q2, -448.f), 448.f);
            q3 = fminf(fmaxf(q3, -448.f), 448.f);
            int pk = __builtin_amdgcn_cvt_pk_fp8_f32(q0, q1, 0, false);
            pk = __builtin_amdgcn_cvt_pk_fp8_f32(q2, q3, pk, true);
            words[i] = (uint32_t)pk;
        }
        const int kt = t >> 2;
        const int ch = t & 3;
        const size_t tile_idx = (size_t)(row >> 7) * (H >> 6) + kt;
        const int c = ((row >> 5) & 3) * 4 + ch;
        uint4 val;
        val.x = words[0]; val.y = words[1]; val.z = words[2]; val.w = words[3];
        *(uint4*)(q + tile_idx * 8192 + c * 512 + (row & 31) * 16) = val;
    }
}

// ---------------------------------------------------------------------------
// helper: load one 32-byte MFMA operand frag from a 2KB frag sub-block
// ---------------------------------------------------------------------------
static __device__ __forceinline__ int8v ldfrag(const uint8_t* p) {
    const uint4 lo = *(const uint4*)p;
    const uint4 hi = *(const uint4*)(p + 512);
    int8v r = {(int)lo.x, (int)lo.y, (int)lo.z, (int)lo.w,
               (int)hi.x, (int)hi.y, (int)hi.z, (int)hi.w};
    return r;
}

// ---------------------------------------------------------------------------
// Kernel 2: MX-fp8 GEMM, barrier-less wave-private pipeline (see header).
// ---------------------------------------------------------------------------
__global__ void __launch_bounds__(256, 1) gemm_fp8_kernel(
    const uint8_t* __restrict__ A,   // q'  frag-tiles
    const uint8_t* __restrict__ B,   // wt' frag-tiles
    float* __restrict__ C,           // out [M][N]
    const float* __restrict__ scale, const float* __restrict__ wscale,
    int M, int N, int K) {
    // 2 slots x (4 waves x 16 KB): wave region = A-image(8K) | B-image(8K)
    __shared__ uint8_t lds[2 * 65536];

    const int t = threadIdx.x;       // 0..255
    const int wid = t >> 6;          // 0..3
    const int lane = t & 63;
    const int wr = wid >> 1;         // 0..1  (M)
    const int wc = wid & 1;          // 0..1  (N)

    // no XCD swizzle: q/wt (100 MB) are L3-fit; m160 measured swizzle costs
    // ~2% in this regime.
    const int wg = blockIdx.x;
    const int nbn = N >> 8;
    const int bm = wg / nbn;
    const int bn = wg % nbn;

    const int nkt = K >> 6;          // 64 tranches of 64 fp8 k-bytes
    // this wave's operand panels (wave tile 128x128)
    const uint8_t* aimg = A + (size_t)(2 * bm + wr) * nkt * 8192;
    const uint8_t* bimg = B + (size_t)(2 * bn + wc) * nkt * 8192;
    const int l16 = lane * 16;
    const int lgl = (lane >> 5) * 1024 + (lane & 31) * 16;

    uint8_t* wb0 = lds + wid * 16384;           // this wave, slot 0
    uint8_t* wb1 = lds + 65536 + wid * 16384;   // this wave, slot 1

    // 16 wave-private gloads: 8 for A image, 8 for B image
#define STAGEW(u, base)                                                        \
    {                                                                          \
        const size_t _o = (size_t)(u) * 8192;                                  \
        _Pragma("unroll") for (int c = 0; c < 8; ++c) {                        \
            GLOAD_LDS16(aimg + _o + c * 1024 + l16, (base) + c * 1024 + l16);  \
            GLOAD_LDS16(bimg + _o + c * 1024 + l16,                            \
                        (base) + 8192 + c * 1024 + l16);                       \
        }                                                                      \
    }

#define READF(base, fa, fb)                                                    \
    {                                                                          \
        _Pragma("unroll") for (int q = 0; q < 4; ++q) {                        \
            fa[q] = ldfrag((base) + q * 2048 + lgl);                           \
            fb[q] = ldfrag((base) + 8192 + q * 2048 + lgl);                    \
        }                                                                      \
    }

#define MFMA16(fa, fb)                                                         \
    {                                                                          \
        _Pragma("unroll") for (int mb = 0; mb < 4; ++mb)                       \
            _Pragma("unroll") for (int nb = 0; nb < 4; ++nb)                   \
                acc[mb][nb] = MFMA_SCALE1(fa[mb], fb[nb], acc[mb][nb]);        \
    }

    float16v acc[4][4] = {};
    int8v fAa[4], fAb[4], fBa[4], fBb[4];

    // prologue: stage tranches 0,1 (32 outstanding); read tranche 0 -> fA
    STAGEW(0, wb0)
    STAGEW(1, wb1)
    asm volatile("s_waitcnt vmcnt(16)" ::: "memory");   // tranche 0 landed
    READF(wb0, fAa, fAb)

    for (int kt = 0; kt < nkt; kt += 2) {
        // ---- even: MFMA tranche kt (fA); read kt+1 -> fB; stage kt+2 ----
        asm volatile("s_waitcnt lgkmcnt(0)" ::: "memory");  // slot0 reads done
        {
            const int u = (kt + 2 < nkt) ? (kt + 2) : (nkt - 1);
            STAGEW(u, wb0)
        }
        asm volatile("s_waitcnt vmcnt(16)" ::: "memory");   // tranche kt+1 in
        READF(wb1, fBa, fBb)
        MFMA16(fAa, fAb)
        // ---- odd: MFMA tranche kt+1 (fB); read kt+2 -> fA; stage kt+3 ----
        asm volatile("s_waitcnt lgkmcnt(0)" ::: "memory");  // slot1 reads done
        {
            const int u = (kt + 3 < nkt) ? (kt + 3) : (nkt - 1);
            STAGEW(u, wb1)
        }
        asm volatile("s_waitcnt vmcnt(16)" ::: "memory");   // tranche kt+2 in
        READF(wb0, fAa, fAb)
        MFMA16(fBa, fBb)
    }
#undef STAGEW
#undef READF
#undef MFMA16

    // epilogue: C/D 32x32 layout col=lane&31, row=(reg&3)+8*(reg>>2)+4*(lane>>5)
    // nontemporal: C is a write-once stream; keep q/wt resident in L3.
    const float f = scale[0] * wscale[0];
    const int col = lane & 31;
    const int rb4 = (lane >> 5) * 4;
#pragma unroll
    for (int mb = 0; mb < 4; ++mb) {
#pragma unroll
        for (int nb = 0; nb < 4; ++nb) {
#pragma unroll
            for (int reg = 0; reg < 16; ++reg) {
                const int r = (reg & 3) + 8 * (reg >> 2) + rb4;
                const size_t gr = (size_t)(bm * 256 + wr * 128 + mb * 32 + r);
                const size_t gc = (size_t)(bn * 256 + wc * 128 + nb * 32 + col);
                __builtin_nontemporal_store(acc[mb][nb][reg] * f, &C[gr * N + gc]);
            }
        }
    }
}

// ---------------------------------------------------------------------------
extern "C" void kernel_launch(void* const* d_in, const int* in_sizes, int n_in,
                              void* d_out, int out_size, void* d_ws, size_t ws_size,
                              hipStream_t stream) {
    const float* hs     = (const float*)d_in[0];
    const float* res    = (const float*)d_in[1];
    const float* nw     = (const float*)d_in[2];
    const float* w      = (const float*)d_in[3];
    const float* scale  = (const float*)d_in[4];
    const float* wscale = (const float*)d_in[5];

    const int H = in_sizes[2];
    const int T = in_sizes[0] / H;
    const int I = in_sizes[3] / H;

    float* out       = (float*)d_out;            // [T][I]
    float* resid_out = out + (size_t)T * I;      // [T][H]
    uint8_t* q  = (uint8_t*)d_ws;                // q'  frag-tiles (T*H bytes)
    uint8_t* wt = q + (size_t)T * H;             // wt' frag-tiles (I*H bytes)

    // 1. fused producers: wconv blocks + norm blocks in one launch
    const int nwb = (I / 64) * (H / 64);
    prep_kernel<<<nwb + T, 256, 0, stream>>>(
        w, wt, hs, res, nw, scale, resid_out, q, H, I, H, nwb);
    // 2. MX-fp8 GEMM + dequant (barrier-less wave-private pipeline)
    gemm_fp8_kernel<<<(T / 256) * (I / 256), 256, 0, stream>>>(
        q, wt, out, scale, wscale, T, I, H);
}